// Round 5
// baseline (745.073 us; speedup 1.0000x reference)
//
#include <hip/hip_runtime.h>

typedef __attribute__((ext_vector_type(4))) float f32x4;
typedef __attribute__((ext_vector_type(16))) float f32x16;
typedef __attribute__((ext_vector_type(8))) short s16x8;

#define MFMA32(a, b, c) __builtin_amdgcn_mfma_f32_32x32x16_bf16((a), (b), (c), 0, 0, 0)

__device__ __forceinline__ float hsig(float x) {
    return fminf(fmaxf(0.2f * x + 0.5f, 0.0f), 1.0f);
}

__device__ __forceinline__ unsigned short bf16rne(float v) {
    unsigned u = __float_as_uint(v);
    u += 0x7FFFu + ((u >> 16) & 1u);
    return (unsigned short)(u >> 16);
}
__device__ __forceinline__ void split2(float v, unsigned short& h, unsigned short& l) {
    h = bf16rne(v);
    float hv = __uint_as_float((unsigned)h << 16);
    l = bf16rne(v - hv);
}

// ---- weight prep: reorder to 32x32x16 MFMA B-fragment order ----
// Bw layout per ks (32 k-values): [ hi: nfrag(8) x kk(2) x lane(64) x 8 | lo ]
// = 16384 ushorts per ks.  B element: col n = nfrag*32+(lane&31),
// k = ks*32 + kk*16 + (lane>>5)*8 + j.
template<int KHW, int CX, int NS>
__global__ __launch_bounds__(256)
void prep_w(const float* __restrict__ Kw, const float* __restrict__ Rw,
            unsigned short* __restrict__ Bw)
{
    int gid = blockIdx.x * 256 + threadIdx.x;
    if (gid >= NS * 1024) return;
    int lane = gid & 63;
    int sub  = (gid >> 6) & 15;   // nfrag*2 + kk
    int ks   = gid >> 10;
    int n  = (sub >> 1) * 32 + (lane & 31);
    int kl = (sub & 1) * 16 + (lane >> 5) * 8;
    constexpr int KX = KHW * CX;
    s16x8 vh, vl;
#pragma unroll
    for (int j = 0; j < 8; ++j) {
        int kg = ks * 32 + kl + j;
        float w = (kg < KX) ? Kw[(long)kg * 256 + n]
                            : Rw[(long)(kg - KX) * 256 + n];
        unsigned short h, l;
        split2(w, h, l);
        vh[j] = (short)h;
        vl[j] = (short)l;
    }
    unsigned short* o = Bw + (long)ks * 16384 + sub * 512 + lane * 8;
    *(s16x8*)o = vh;
    *(s16x8*)(o + 8192) = vl;
}

// ---- stage zero-padded tile as bf16 hi/lo planes, chunk-major [c/8][pixel][8] ----
template<int C, int TS, int PAD, int CST>
__device__ __forceinline__ void stage_split(const float* __restrict__ gp,
                                            unsigned short* __restrict__ hi_,
                                            unsigned short* __restrict__ lo_,
                                            int ty0, int tx0, int tid)
{
    constexpr int CH = C / 8;
    constexpr int NP = TS * TS;
    for (int i = tid; i < NP * CH; i += 512) {
        int ch = i % CH;
        int p  = i / CH;
        int py = p / TS, px = p % TS;
        int iy = ty0 + py - PAD, ix = tx0 + px - PAD;
        float v[8];
        if (iy >= 0 && iy < 64 && ix >= 0 && ix < 64) {
            const float* s = gp + ((long)(iy * 64 + ix)) * C + ch * 8;
            f32x4 a = *(const f32x4*)s;
            f32x4 b = *(const f32x4*)(s + 4);
#pragma unroll
            for (int j = 0; j < 4; ++j) { v[j] = a[j]; v[4 + j] = b[j]; }
        } else {
#pragma unroll
            for (int j = 0; j < 8; ++j) v[j] = 0.0f;
        }
        s16x8 vh, vl;
#pragma unroll
        for (int j = 0; j < 8; ++j) {
            unsigned short h, l;
            split2(v[j], h, l);
            vh[j] = (short)h;
            vl[j] = (short)l;
        }
        *(s16x8*)(hi_ + ch * CST + p * 8) = vh;
        *(s16x8*)(lo_ + ch * CST + p * 8) = vl;
    }
}

// ---- fused ConvLSTM step, 32x32x16 MFMA, 3-pass hi/lo ----
// M=64 pixels (8x8 tile) = 2 M-frags(32), N=256 = 8 N-frags(32).
// Wave map: 8 waves = 2 K-groups x 4 N-quarters (nq owns 2 N-frags = 64 cols,
// all 64 px, half the k-steps).  24 MFMA/wave/k-step (was 48 at 16x16):
// half the issue slots, -17% matrix-pipe cycles (2382 vs 2075 TF shape).
template<int KW, int CX, int TS, int NS, int XS>
__global__ __launch_bounds__(512, 2)
void lstm_mfma(const float* __restrict__ xin, long xbstride,
               const float* __restrict__ hin,
               const unsigned short* __restrict__ Bg,
               const float* __restrict__ bias,
               float* __restrict__ c_buf,
               float* __restrict__ h_out,
               float* __restrict__ y_out, long ybstride)
{
    constexpr int PAD = KW / 2;
    constexpr int NP  = TS * TS;
    constexpr int CHX = CX / 8;
    constexpr int CST = NP * 8;              // chunk stride (ushorts)
    constexpr int XPLANE = CHX * CST;
    constexpr int HPLANE = 8 * CST;
    constexpr int STAGEU = 2 * XPLANE + 2 * HPLANE;
    constexpr int ZST = 260;                 // z row stride (f32)
    constexpr int ZPL = 32 * ZST;            // per-K-group plane (f32)
    constexpr int ZLU = 2 * ZPL * 2;         // ushort count
    constexpr int SMEMU = STAGEU > ZLU ? STAGEU : ZLU;
    constexpr int SPLIT = (NS + 1) / 2;      // k-group boundary
    __shared__ __align__(16) unsigned short smem[SMEMU];

    unsigned short* sxh = smem;
    unsigned short* sxl = sxh + XPLANE;
    unsigned short* shh = sxl + XPLANE;
    unsigned short* shl = shh + HPLANE;

    const int tid  = threadIdx.x;
    const int lane = tid & 63, wid = tid >> 6;
    const int nq = wid & 3;                  // N-quarter: columns [64nq, 64nq+64)
    const int kg = wid >> 2;                 // K-group
    const int b   = blockIdx.z;
    const int ty0 = blockIdx.y * 8, tx0 = blockIdx.x * 8;

    const int ks0 = kg ? SPLIT : 0;
    const int ks1 = kg ? NS : SPLIT;

    // B fragment base: wave owns nfrags {2nq, 2nq+1}
    const unsigned short* bp = Bg + (long)ks0 * 16384 + (nq * 2) * 1024 + lane * 8;

    // Bh/Bl index: nf*2 + kk
    s16x8 Bh[2][4], Bl[2][4];
#define LOADB(BI, Q)                                             \
    {                                                            \
        const unsigned short* q_ = (Q);                          \
        _Pragma("unroll")                                        \
        for (int t_ = 0; t_ < 4; ++t_) {                         \
            Bh[BI][t_] = *(const s16x8*)(q_ + t_ * 512);         \
            Bl[BI][t_] = *(const s16x8*)(q_ + 8192 + t_ * 512);  \
        }                                                        \
    }

    LOADB(0, bp);             // first k-step, overlaps with staging

    stage_split<CX, TS, PAD, CST>(xin + (long)b * xbstride, sxh, sxl, ty0, tx0, tid);
    stage_split<64, TS, PAD, CST>(hin + (long)b * 4096 * 64, shh, shl, ty0, tx0, tid);
    __syncthreads();

    f32x16 acc[2][2];
#pragma unroll
    for (int mf = 0; mf < 2; ++mf)
#pragma unroll
        for (int nf = 0; nf < 2; ++nf)
#pragma unroll
            for (int q = 0; q < 16; ++q) acc[mf][nf][q] = 0.0f;

    // thread-const A offsets (ushort units). pixel p = mf*32 + (lane&31),
    // k-octet o = (lane>>5) + 2*kk at LDS chunk offset o*CST.
    const int pb   = lane & 31;
    const int koct = (lane >> 5) * CST;
    const int av0  = ((pb >> 3) * TS + (pb & 7)) * 8 + koct;
    const int av1  = av0 + 4 * TS * 8;

    // Ar index: hi mf*2+kk at [0..3], lo at [4..7]
    s16x8 Ar[2][8];
#define LOADA(AI, KS)                                                    \
    {                                                                    \
        int ksv_ = (KS);                                                 \
        int tap_, cb8_;                                                  \
        const unsigned short *ph_, *pl_;                                 \
        if (ksv_ < XS) {                                                 \
            if (CX == 32) { tap_ = ksv_; cb8_ = 0; }                     \
            else { tap_ = ksv_ >> 1; cb8_ = (ksv_ & 1) * 4; }            \
            ph_ = sxh; pl_ = sxl;                                        \
        } else {                                                         \
            int kk_ = ksv_ - XS;                                         \
            tap_ = kk_ >> 1; cb8_ = (kk_ & 1) * 4;                       \
            ph_ = shh; pl_ = shl;                                        \
        }                                                                \
        int kh_ = tap_ / KW, kw_ = tap_ - kh_ * KW;                      \
        int so_ = cb8_ * CST + (kh_ * TS + kw_) * 8;                     \
        Ar[AI][0] = *(const s16x8*)(ph_ + so_ + av0);                    \
        Ar[AI][1] = *(const s16x8*)(ph_ + so_ + av0 + 2 * CST);          \
        Ar[AI][2] = *(const s16x8*)(ph_ + so_ + av1);                    \
        Ar[AI][3] = *(const s16x8*)(ph_ + so_ + av1 + 2 * CST);          \
        Ar[AI][4] = *(const s16x8*)(pl_ + so_ + av0);                    \
        Ar[AI][5] = *(const s16x8*)(pl_ + so_ + av0 + 2 * CST);          \
        Ar[AI][6] = *(const s16x8*)(pl_ + so_ + av1);                    \
        Ar[AI][7] = *(const s16x8*)(pl_ + so_ + av1 + 2 * CST);          \
    }

    // 3 passes: ah*bh, al*bh, ah*bl ; 4 independent acc chains, 24 MFMA total
#define MM(AI, BI)                                                            \
    {                                                                         \
        _Pragma("unroll")                                                     \
        for (int kk = 0; kk < 2; ++kk)                                        \
        {                                                                     \
            _Pragma("unroll")                                                 \
            for (int nf = 0; nf < 2; ++nf)                                    \
            {                                                                 \
                _Pragma("unroll")                                             \
                for (int mf = 0; mf < 2; ++mf)                                \
                    acc[mf][nf] = MFMA32(Ar[AI][mf * 2 + kk],                 \
                                         Bh[BI][nf * 2 + kk], acc[mf][nf]);   \
            }                                                                 \
        }                                                                     \
        _Pragma("unroll")                                                     \
        for (int kk = 0; kk < 2; ++kk)                                        \
        {                                                                     \
            _Pragma("unroll")                                                 \
            for (int nf = 0; nf < 2; ++nf)                                    \
            {                                                                 \
                _Pragma("unroll")                                             \
                for (int mf = 0; mf < 2; ++mf)                                \
                    acc[mf][nf] = MFMA32(Ar[AI][4 + mf * 2 + kk],             \
                                         Bh[BI][nf * 2 + kk], acc[mf][nf]);   \
            }                                                                 \
        }                                                                     \
        _Pragma("unroll")                                                     \
        for (int kk = 0; kk < 2; ++kk)                                        \
        {                                                                     \
            _Pragma("unroll")                                                 \
            for (int nf = 0; nf < 2; ++nf)                                    \
            {                                                                 \
                _Pragma("unroll")                                             \
                for (int mf = 0; mf < 2; ++mf)                                \
                    acc[mf][nf] = MFMA32(Ar[AI][mf * 2 + kk],                 \
                                         Bl[BI][nf * 2 + kk], acc[mf][nf]);   \
            }                                                                 \
        }                                                                     \
    }

    LOADA(0, ks0);

    const unsigned short* bq = bp;
    int ks = ks0;
#pragma unroll 1
    for (; ks + 1 < ks1; ks += 2, bq += 32768) {
        LOADB(1, bq + 16384);
        LOADA(1, ks + 1);
        MM(0, 0);
        if (ks + 2 < ks1) {
            LOADB(0, bq + 32768);
            LOADA(0, ks + 2);
        }
        MM(1, 1);
    }
    if (ks < ks1) MM(0, 0);   // odd-count tail (buf0 holds ks)

    // ---- z exchange: per-K-group planes, 2 rounds of 32 pixels ----
    // C/D layout (32x32): col = lane&31, row = (r&3) + 8*(r>>2) + 4*(lane>>5).
    // Round RR exchanges acc[RR][*] (pixels RR*32 .. RR*32+31).
    __syncthreads();
    float* zl = (float*)smem;  // [kg][32][ZST] f32 = 66.5 KB overlay
    const int f = tid & 63;
    const float bi = bias[f], bfr = bias[64 + f], bg = bias[128 + f], bo = bias[192 + f];

#define ZROUND(RR)                                                            \
    {                                                                         \
        _Pragma("unroll")                                                     \
        for (int nf = 0; nf < 2; ++nf)                                        \
        {                                                                     \
            _Pragma("unroll")                                                 \
            for (int r = 0; r < 16; ++r) {                                    \
                int pl_ = (r & 3) + 8 * (r >> 2) + 4 * (lane >> 5);           \
                int c   = nq * 64 + nf * 32 + (lane & 31);                    \
                zl[kg * ZPL + pl_ * ZST + (c & 63) * 4 + (c >> 6)] =          \
                    acc[RR][nf][r];                                           \
            }                                                                 \
        }                                                                     \
        __syncthreads();                                                      \
        _Pragma("unroll")                                                     \
        for (int j = 0; j < 4; ++j) {                                         \
            int pl_ = (tid >> 6) + j * 8;                                     \
            int p   = (RR) * 32 + pl_;                                        \
            f32x4 za = *(const f32x4*)(zl + pl_ * ZST + f * 4);               \
            f32x4 zb = *(const f32x4*)(zl + ZPL + pl_ * ZST + f * 4);         \
            float zi = za[0] + zb[0] + bi, zf = za[1] + zb[1] + bfr;          \
            float zg = za[2] + zb[2] + bg, zo = za[3] + zb[3] + bo;           \
            int y = ty0 + (p >> 3), x = tx0 + (p & 7);                        \
            long o = ((long)((b * 64 + y) * 64 + x)) * 64 + f;                \
            float cv = c_buf[o];                                              \
            float cn = hsig(zf) * cv + hsig(zi) * tanhf(zg);                  \
            c_buf[o] = cn;                                                    \
            float hn = hsig(zo) * tanhf(cn);                                  \
            h_out[o] = hn;                                                    \
            y_out[(long)b * ybstride + ((long)(y * 64 + x)) * 64 + f] =       \
                fmaxf(hn, 0.0f);                                              \
        }                                                                     \
        __syncthreads();                                                      \
    }

    ZROUND(0)
    ZROUND(1)

#undef LOADB
#undef LOADA
#undef MM
#undef ZROUND
}

extern "C" void kernel_launch(void* const* d_in, const int* in_sizes, int n_in,
                              void* d_out, int out_size, void* d_ws, size_t ws_size,
                              hipStream_t stream)
{
    const float* x  = (const float*)d_in[0];
    const float* K1 = (const float*)d_in[1];
    const float* R1 = (const float*)d_in[2];
    const float* b1 = (const float*)d_in[3];
    const float* K2 = (const float*)d_in[4];
    const float* R2 = (const float*)d_in[5];
    const float* b2 = (const float*)d_in[6];
    float* out = (float*)d_out;

    const long HW   = 4096;
    const long SZ_S = HW * 64 * 4;      // 1,048,576 floats per [B,H,W,64]
    const long SZ_Y = SZ_S * 8;

    float* ws  = (float*)d_ws;
    float* y1  = ws;                    // 8,388,608 f32
    float* h_a = y1 + SZ_Y;             // 1,048,576
    float* h_b = h_a + SZ_S;
    float* c   = h_b + SZ_S;
    unsigned short* B1 = (unsigned short*)(c + SZ_S);   // 75*16384 ushorts
    unsigned short* B2 = B1 + (long)75 * 16384;         // 36*16384 ushorts

    // weight prep
    prep_w<25, 32, 75><<<300, 256, 0, stream>>>(K1, R1, B1);
    prep_w<9,  64, 36><<<144, 256, 0, stream>>>(K2, R2, B2);

    dim3 grid(8, 8, 4);
    dim3 blk(512);

    // ---- layer 1: 5x5, Cin=32, K=2400 (75 ksteps, 25 x-steps) ----
    hipMemsetAsync(h_a, 0, (size_t)SZ_S * sizeof(float), stream);
    hipMemsetAsync(c,   0, (size_t)SZ_S * sizeof(float), stream);
    {
        float* hp = h_a;
        float* hn = h_b;
        for (int t = 0; t < 8; ++t) {
            lstm_mfma<5, 32, 12, 75, 25><<<grid, blk, 0, stream>>>(
                x + (long)t * HW * 32, (long)8 * HW * 32,
                hp, B1, b1, c, hn,
                y1 + (long)t * HW * 64, (long)8 * HW * 64);
            float* tmp = hp; hp = hn; hn = tmp;
        }
    }

    // ---- layer 2: 3x3, Cin=64, K=1152 (36 ksteps, 18 x-steps) ----
    hipMemsetAsync(h_a, 0, (size_t)SZ_S * sizeof(float), stream);
    hipMemsetAsync(c,   0, (size_t)SZ_S * sizeof(float), stream);
    {
        float* hp = h_a;
        float* hn = h_b;
        for (int t = 0; t < 8; ++t) {
            lstm_mfma<3, 64, 10, 36, 18><<<grid, blk, 0, stream>>>(
                y1 + (long)t * HW * 64, (long)8 * HW * 64,
                hp, B2, b2, c, hn,
                out + (long)t * HW * 64, (long)8 * HW * 64);
            float* tmp = hp; hp = hn; hn = tmp;
        }
    }
}

// Round 6
// 657.794 us; speedup vs baseline: 1.1327x; 1.1327x over previous
//
#include <hip/hip_runtime.h>

typedef __attribute__((ext_vector_type(4))) float f32x4;
typedef __attribute__((ext_vector_type(8))) short s16x8;

#define MFMA16(a, b, c) __builtin_amdgcn_mfma_f32_16x16x32_bf16((a), (b), (c), 0, 0, 0)

__device__ __forceinline__ float hsig(float x) {
    return fminf(fmaxf(0.2f * x + 0.5f, 0.0f), 1.0f);
}

__device__ __forceinline__ unsigned short bf16rne(float v) {
    unsigned u = __float_as_uint(v);
    u += 0x7FFFu + ((u >> 16) & 1u);
    return (unsigned short)(u >> 16);
}
__device__ __forceinline__ void split2(float v, unsigned short& h, unsigned short& l) {
    h = bf16rne(v);
    float hv = __uint_as_float((unsigned)h << 16);
    l = bf16rne(v - hv);
}

// ---- weight prep: reorder to MFMA B-fragment order ----
// Bw layout: [ks][ hi: nfrag(16) x lane(64) x 8 | lo: same ]  (16384 ushorts per ks)
template<int KHW, int CX, int NS>
__global__ __launch_bounds__(256)
void prep_w(const float* __restrict__ Kw, const float* __restrict__ Rw,
            unsigned short* __restrict__ Bw)
{
    int gid = blockIdx.x * 256 + threadIdx.x;
    if (gid >= NS * 1024) return;
    int lane  = gid & 63;
    int nfrag = (gid >> 6) & 15;
    int ks    = gid >> 10;
    int n  = nfrag * 16 + (lane & 15);
    int kl = (lane >> 4) * 8;
    constexpr int KX = KHW * CX;
    s16x8 vh, vl;
#pragma unroll
    for (int j = 0; j < 8; ++j) {
        int kg = ks * 32 + kl + j;
        float w = (kg < KX) ? Kw[(long)kg * 256 + n]
                            : Rw[(long)(kg - KX) * 256 + n];
        unsigned short h, l;
        split2(w, h, l);
        vh[j] = (short)h;
        vl[j] = (short)l;
    }
    unsigned short* o = Bw + (long)ks * 16384 + nfrag * 512 + lane * 8;
    *(s16x8*)o = vh;
    *(s16x8*)(o + 8192) = vl;
}

// ---- stage zero-padded tile as bf16 hi/lo planes, chunk-major [c/8][pixel][8] ----
// CST padded +8 ushorts: chunk stride 2320B (L1) / 1616B (L2) -> k-quarter and
// stage-write chunk strides land on distinct banks instead of all bank 0.
template<int C, int TS, int PAD, int CST>
__device__ __forceinline__ void stage_split(const float* __restrict__ gp,
                                            unsigned short* __restrict__ hi_,
                                            unsigned short* __restrict__ lo_,
                                            int ty0, int tx0, int tid)
{
    constexpr int CH = C / 8;
    constexpr int NP = TS * TS;
    for (int i = tid; i < NP * CH; i += 512) {
        int ch = i % CH;
        int p  = i / CH;
        int py = p / TS, px = p % TS;
        int iy = ty0 + py - PAD, ix = tx0 + px - PAD;
        float v[8];
        if (iy >= 0 && iy < 64 && ix >= 0 && ix < 64) {
            const float* s = gp + ((long)(iy * 64 + ix)) * C + ch * 8;
            f32x4 a = *(const f32x4*)s;
            f32x4 b = *(const f32x4*)(s + 4);
#pragma unroll
            for (int j = 0; j < 4; ++j) { v[j] = a[j]; v[4 + j] = b[j]; }
        } else {
#pragma unroll
            for (int j = 0; j < 8; ++j) v[j] = 0.0f;
        }
        s16x8 vh, vl;
#pragma unroll
        for (int j = 0; j < 8; ++j) {
            unsigned short h, l;
            split2(v[j], h, l);
            vh[j] = (short)h;
            vl[j] = (short)l;
        }
        *(s16x8*)(hi_ + ch * CST + p * 8) = vh;
        *(s16x8*)(lo_ + ch * CST + p * 8) = vl;
    }
}

// ---- fused ConvLSTM step, MFMA 3-pass hi/lo (r4 structure + pad + setprio) ----
// M=64 pixels (8x8 tile), N=256 gate-channels, K = KHW*(CX+64).
// Wave map: 8 waves = 2 K-groups x 4 N-quarters. Each wave owns all 64
// pixels x 64 columns x half the k-steps (partial sums, summed in z-exchange).
template<int KW, int CX, int TS, int NS, int XS>
__global__ __launch_bounds__(512, 2)
void lstm_mfma(const float* __restrict__ xin, long xbstride,
               const float* __restrict__ hin,
               const unsigned short* __restrict__ Bg,
               const float* __restrict__ bias,
               float* __restrict__ c_buf,
               float* __restrict__ h_out,
               float* __restrict__ y_out, long ybstride)
{
    constexpr int PAD = KW / 2;
    constexpr int NP  = TS * TS;
    constexpr int CHX = CX / 8;
    constexpr int CST = NP * 8 + 8;          // padded chunk stride (ushorts)
    constexpr int XPLANE = CHX * CST;
    constexpr int HPLANE = 8 * CST;
    constexpr int STAGEU = 2 * XPLANE + 2 * HPLANE;
    constexpr int ZST = 260;                 // z row stride (f32)
    constexpr int ZPL = 32 * ZST;            // per-K-group plane (f32)
    constexpr int ZLU = 2 * ZPL * 2;         // ushort count
    constexpr int SMEMU = STAGEU > ZLU ? STAGEU : ZLU;
    constexpr int SPLIT = (NS + 1) / 2;      // k-group boundary
    __shared__ __align__(16) unsigned short smem[SMEMU];

    unsigned short* sxh = smem;
    unsigned short* sxl = sxh + XPLANE;
    unsigned short* shh = sxl + XPLANE;
    unsigned short* shl = shh + HPLANE;

    const int tid  = threadIdx.x;
    const int lane = tid & 63, wid = tid >> 6;
    const int nq = wid & 3;                  // N-quarter: columns [64nq, 64nq+64)
    const int kg = wid >> 2;                 // K-group
    const int b   = blockIdx.z;
    const int ty0 = blockIdx.y * 8, tx0 = blockIdx.x * 8;

    const int ks0 = kg ? SPLIT : 0;
    const int ks1 = kg ? NS : SPLIT;

    // B fragment base: wave owns nfrags [4nq, 4nq+4), starting at k-step ks0
    const unsigned short* bp = Bg + (long)ks0 * 16384 + (nq * 4) * 512 + lane * 8;

    s16x8 Bh[2][4], Bl[2][4];
#define LOADB(BI, Q)                                             \
    {                                                            \
        const unsigned short* q_ = (Q);                          \
        _Pragma("unroll")                                        \
        for (int nf = 0; nf < 4; ++nf) {                         \
            Bh[BI][nf] = *(const s16x8*)(q_ + nf * 512);         \
            Bl[BI][nf] = *(const s16x8*)(q_ + 8192 + nf * 512);  \
        }                                                        \
    }

    LOADB(0, bp);             // first k-step, overlaps with staging

    stage_split<CX, TS, PAD, CST>(xin + (long)b * xbstride, sxh, sxl, ty0, tx0, tid);
    stage_split<64, TS, PAD, CST>(hin + (long)b * 4096 * 64, shh, shl, ty0, tx0, tid);
    __syncthreads();

    f32x4 acc[4][4];
#pragma unroll
    for (int mf = 0; mf < 4; ++mf)
#pragma unroll
        for (int nf = 0; nf < 4; ++nf)
#pragma unroll
            for (int q = 0; q < 4; ++q) acc[mf][nf][q] = 0.0f;

    // thread-const A offsets (ushort units). pixel p = mf*16 + (lane&15)
    const int pb  = lane & 15;
    const int kq  = (lane >> 4) * CST;
    const int av0 = (((pb      >> 3) * TS) + (pb      & 7)) * 8 + kq;
    const int av1 = ((((pb+16) >> 3) * TS) + ((pb+16) & 7)) * 8 + kq;
    const int av2 = ((((pb+32) >> 3) * TS) + ((pb+32) & 7)) * 8 + kq;
    const int av3 = ((((pb+48) >> 3) * TS) + ((pb+48) & 7)) * 8 + kq;

    s16x8 Ar[2][8];  // [buf][ mf0..3 hi | mf0..3 lo ]
#define LOADA(AI, KS)                                                    \
    {                                                                    \
        int ksv_ = (KS);                                                 \
        int tap_, cb8_;                                                  \
        const unsigned short *ph_, *pl_;                                 \
        if (ksv_ < XS) {                                                 \
            if (CX == 32) { tap_ = ksv_; cb8_ = 0; }                     \
            else { tap_ = ksv_ >> 1; cb8_ = (ksv_ & 1) * 4; }            \
            ph_ = sxh; pl_ = sxl;                                        \
        } else {                                                         \
            int kk_ = ksv_ - XS;                                         \
            tap_ = kk_ >> 1; cb8_ = (kk_ & 1) * 4;                       \
            ph_ = shh; pl_ = shl;                                        \
        }                                                                \
        int kh_ = tap_ / KW, kw_ = tap_ - kh_ * KW;                      \
        int so_ = cb8_ * CST + (kh_ * TS + kw_) * 8;                     \
        Ar[AI][0] = *(const s16x8*)(ph_ + so_ + av0);                    \
        Ar[AI][1] = *(const s16x8*)(ph_ + so_ + av1);                    \
        Ar[AI][2] = *(const s16x8*)(ph_ + so_ + av2);                    \
        Ar[AI][3] = *(const s16x8*)(ph_ + so_ + av3);                    \
        Ar[AI][4] = *(const s16x8*)(pl_ + so_ + av0);                    \
        Ar[AI][5] = *(const s16x8*)(pl_ + so_ + av1);                    \
        Ar[AI][6] = *(const s16x8*)(pl_ + so_ + av2);                    \
        Ar[AI][7] = *(const s16x8*)(pl_ + so_ + av3);                    \
    }

    // 3 passes: ah*bh, al*bh, ah*bl ; 16 independent acc chains.
    // setprio(1) across the pure-MFMA cluster (T5): k-groups are desynced,
    // so the scheduler can favor the MFMA-entering wave over load-issuers.
#define MM(AI, BI)                                                        \
    {                                                                     \
        __builtin_amdgcn_s_setprio(1);                                    \
        _Pragma("unroll")                                                 \
        for (int nf = 0; nf < 4; ++nf)                                    \
        {                                                                 \
            _Pragma("unroll")                                             \
            for (int mf = 0; mf < 4; ++mf)                                \
                acc[mf][nf] = MFMA16(Ar[AI][mf], Bh[BI][nf], acc[mf][nf]);\
        }                                                                 \
        _Pragma("unroll")                                                 \
        for (int nf = 0; nf < 4; ++nf)                                    \
        {                                                                 \
            _Pragma("unroll")                                             \
            for (int mf = 0; mf < 4; ++mf)                                \
                acc[mf][nf] = MFMA16(Ar[AI][4+mf], Bh[BI][nf], acc[mf][nf]);\
        }                                                                 \
        _Pragma("unroll")                                                 \
        for (int nf = 0; nf < 4; ++nf)                                    \
        {                                                                 \
            _Pragma("unroll")                                             \
            for (int mf = 0; mf < 4; ++mf)                                \
                acc[mf][nf] = MFMA16(Ar[AI][mf], Bl[BI][nf], acc[mf][nf]);\
        }                                                                 \
        __builtin_amdgcn_s_setprio(0);                                    \
    }

    LOADA(0, ks0);

    const unsigned short* bq = bp;
    int ks = ks0;
#pragma unroll 1
    for (; ks + 1 < ks1; ks += 2, bq += 32768) {
        LOADB(1, bq + 16384);
        LOADA(1, ks + 1);
        MM(0, 0);
        if (ks + 2 < ks1) {
            LOADB(0, bq + 32768);
            LOADA(0, ks + 2);
        }
        MM(1, 1);
    }
    if (ks < ks1) MM(0, 0);   // odd-count tail (buf0 holds ks)

    // ---- z exchange: per-K-group planes, 2 rounds of 32 pixels ----
    __syncthreads();
    float* zl = (float*)smem;  // [kg][32][ZST] f32 = 66.5 KB overlay
    const int f = tid & 63;
    const float bi = bias[f], bfr = bias[64 + f], bg = bias[128 + f], bo = bias[192 + f];

#define ZROUND(RR)                                                            \
    {                                                                         \
        _Pragma("unroll")                                                     \
        for (int mi = 0; mi < 2; ++mi)                                        \
        {                                                                     \
            _Pragma("unroll")                                                 \
            for (int nf = 0; nf < 4; ++nf)                                    \
            {                                                                 \
                _Pragma("unroll")                                             \
                for (int q = 0; q < 4; ++q) {                                 \
                    int pl_ = mi * 16 + (lane >> 4) * 4 + q;                  \
                    int c   = nq * 64 + nf * 16 + (lane & 15);                \
                    zl[kg * ZPL + pl_ * ZST + (c & 63) * 4 + (c >> 6)] =      \
                        acc[2 * (RR) + mi][nf][q];                            \
                }                                                             \
            }                                                                 \
        }                                                                     \
        __syncthreads();                                                      \
        _Pragma("unroll")                                                     \
        for (int j = 0; j < 4; ++j) {                                         \
            int pl_ = (tid >> 6) + j * 8;                                     \
            int p   = (RR) * 32 + pl_;                                        \
            f32x4 za = *(const f32x4*)(zl + pl_ * ZST + f * 4);               \
            f32x4 zb = *(const f32x4*)(zl + ZPL + pl_ * ZST + f * 4);         \
            float zi = za[0] + zb[0] + bi, zf = za[1] + zb[1] + bfr;          \
            float zg = za[2] + zb[2] + bg, zo = za[3] + zb[3] + bo;           \
            int y = ty0 + (p >> 3), x = tx0 + (p & 7);                        \
            long o = ((long)((b * 64 + y) * 64 + x)) * 64 + f;                \
            float cv = c_buf[o];                                              \
            float cn = hsig(zf) * cv + hsig(zi) * tanhf(zg);                  \
            c_buf[o] = cn;                                                    \
            float hn = hsig(zo) * tanhf(cn);                                  \
            h_out[o] = hn;                                                    \
            y_out[(long)b * ybstride + ((long)(y * 64 + x)) * 64 + f] =       \
                fmaxf(hn, 0.0f);                                              \
        }                                                                     \
        __syncthreads();                                                      \
    }

    ZROUND(0)
    ZROUND(1)

#undef LOADB
#undef LOADA
#undef MM
#undef ZROUND
}

extern "C" void kernel_launch(void* const* d_in, const int* in_sizes, int n_in,
                              void* d_out, int out_size, void* d_ws, size_t ws_size,
                              hipStream_t stream)
{
    const float* x  = (const float*)d_in[0];
    const float* K1 = (const float*)d_in[1];
    const float* R1 = (const float*)d_in[2];
    const float* b1 = (const float*)d_in[3];
    const float* K2 = (const float*)d_in[4];
    const float* R2 = (const float*)d_in[5];
    const float* b2 = (const float*)d_in[6];
    float* out = (float*)d_out;

    const long HW   = 4096;
    const long SZ_S = HW * 64 * 4;      // 1,048,576 floats per [B,H,W,64]
    const long SZ_Y = SZ_S * 8;

    float* ws  = (float*)d_ws;
    float* y1  = ws;                    // 8,388,608 f32
    float* h_a = y1 + SZ_Y;             // 1,048,576
    float* h_b = h_a + SZ_S;
    float* c   = h_b + SZ_S;
    unsigned short* B1 = (unsigned short*)(c + SZ_S);   // 75*16384 ushorts
    unsigned short* B2 = B1 + (long)75 * 16384;         // 36*16384 ushorts

    // weight prep
    prep_w<25, 32, 75><<<300, 256, 0, stream>>>(K1, R1, B1);
    prep_w<9,  64, 36><<<144, 256, 0, stream>>>(K2, R2, B2);

    dim3 grid(8, 8, 4);
    dim3 blk(512);

    // ---- layer 1: 5x5, Cin=32, K=2400 (75 ksteps, 25 x-steps) ----
    hipMemsetAsync(h_a, 0, (size_t)SZ_S * sizeof(float), stream);
    hipMemsetAsync(c,   0, (size_t)SZ_S * sizeof(float), stream);
    {
        float* hp = h_a;
        float* hn = h_b;
        for (int t = 0; t < 8; ++t) {
            lstm_mfma<5, 32, 12, 75, 25><<<grid, blk, 0, stream>>>(
                x + (long)t * HW * 32, (long)8 * HW * 32,
                hp, B1, b1, c, hn,
                y1 + (long)t * HW * 64, (long)8 * HW * 64);
            float* tmp = hp; hp = hn; hn = tmp;
        }
    }

    // ---- layer 2: 3x3, Cin=64, K=1152 (36 ksteps, 18 x-steps) ----
    hipMemsetAsync(h_a, 0, (size_t)SZ_S * sizeof(float), stream);
    hipMemsetAsync(c,   0, (size_t)SZ_S * sizeof(float), stream);
    {
        float* hp = h_a;
        float* hn = h_b;
        for (int t = 0; t < 8; ++t) {
            lstm_mfma<3, 64, 10, 36, 18><<<grid, blk, 0, stream>>>(
                y1 + (long)t * HW * 64, (long)8 * HW * 64,
                hp, B2, b2, c, hn,
                out + (long)t * HW * 64, (long)8 * HW * 64);
            float* tmp = hp; hp = hn; hn = tmp;
        }
    }
}